// Round 2
// baseline (787.197 us; speedup 1.0000x reference)
//
#include <hip/hip_runtime.h>
#include <hip/hip_bf16.h>

#define M_TOT 16384
#define DIN 2048
#define DOUT 2048

typedef unsigned short u16;
typedef __attribute__((ext_vector_type(8))) short short8;
typedef __attribute__((ext_vector_type(4))) float f32x4;

__device__ __forceinline__ u16 f2bf(float f){
  union { __hip_bfloat16 h; u16 u; } c; c.h = __float2bfloat16(f); return c.u;
}
__device__ __forceinline__ float bf2f(u16 v){
  union { __hip_bfloat16 h; u16 u; } c; c.u = v; return __bfloat162float(c.h);
}

__device__ __forceinline__ void gload16(const void* g, void* lds){
  __builtin_amdgcn_global_load_lds((const __attribute__((address_space(1))) unsigned int*)g,
                                   (__attribute__((address_space(3))) unsigned int*)lds, 16, 0, 0);
}

// ---- W fp32 -> (hi,lo) bf16 split, 4 elems/thread ----
__global__ __launch_bounds__(256) void conv_hilo(const float* __restrict__ src,
                                                 u16* __restrict__ hi, u16* __restrict__ lo){
  size_t i = ((size_t)blockIdx.x * 256 + threadIdx.x) * 4;
  float4 v = *(const float4*)(src + i);
  float vv[4] = {v.x, v.y, v.z, v.w};
  u16 hh[4], ll[4];
#pragma unroll
  for (int e = 0; e < 4; ++e){
    u16 hb = f2bf(vv[e]); hh[e] = hb; ll[e] = f2bf(vv[e] - bf2f(hb));
  }
  *(ushort4*)(hi + i) = make_ushort4(hh[0],hh[1],hh[2],hh[3]);
  *(ushort4*)(lo + i) = make_ushort4(ll[0],ll[1],ll[2],ll[3]);
}

// ---- B fp32 -> bf16 ----
__global__ __launch_bounds__(256) void conv_bf(const float* __restrict__ src, u16* __restrict__ dst){
  int i = blockIdx.x * 256 + threadIdx.x;
  dst[i] = f2bf(src[i]);
}

// ---- z = x@A^T (fp32), top-16 threshold, write z*2 as bf16.
//      Also emits Xhi/Xlo bf16 split of x (x is read here exactly once). ----
__global__ __launch_bounds__(256) void zk(const float* __restrict__ x, const float* __restrict__ A,
                                          u16* __restrict__ Xhi, u16* __restrict__ Xlo,
                                          u16* __restrict__ zb){
  __shared__ float xs[64*64];
  __shared__ float As[64*64];   // k4-slot swizzled: slot' = slot ^ (row>>2)
  const int t = threadIdx.x;
  const int row0 = blockIdx.x * 64;
  const int tm = t >> 4, tn = t & 15;
  float acc[4][4] = {};

  for (int kc = 0; kc < 32; ++kc){
    const int k0 = kc * 64;
    __syncthreads();
#pragma unroll
    for (int rep = 0; rep < 4; ++rep){
      int idx = rep * 256 + t;
      int r = idx >> 4, sl = idx & 15;
      size_t gx_off = (size_t)(row0 + r) * DIN + k0 + sl * 4;
      float4 gx = *(const float4*)(x + gx_off);
      *(float4*)&xs[r*64 + sl*4] = gx;
      float vv[4] = {gx.x, gx.y, gx.z, gx.w};
      u16 hh[4], ll[4];
#pragma unroll
      for (int e = 0; e < 4; ++e){
        u16 hb = f2bf(vv[e]); hh[e] = hb; ll[e] = f2bf(vv[e] - bf2f(hb));
      }
      *(ushort4*)(Xhi + gx_off) = make_ushort4(hh[0],hh[1],hh[2],hh[3]);
      *(ushort4*)(Xlo + gx_off) = make_ushort4(ll[0],ll[1],ll[2],ll[3]);
      float4 ga = *(const float4*)(A + (size_t)r * DIN + k0 + sl * 4);
      int slA = sl ^ (r >> 2);
      *(float4*)&As[r*64 + slA*4] = ga;
    }
    __syncthreads();
#pragma unroll
    for (int k4 = 0; k4 < 16; ++k4){
      float4 xv[4], wv[4];
#pragma unroll
      for (int i = 0; i < 4; ++i) xv[i] = *(const float4*)&xs[(tm*4+i)*64 + k4*4];
#pragma unroll
      for (int j = 0; j < 4; ++j) wv[j] = *(const float4*)&As[(tn*4+j)*64 + ((k4 ^ tn) & 15)*4];
#pragma unroll
      for (int i = 0; i < 4; ++i)
#pragma unroll
        for (int j = 0; j < 4; ++j)
          acc[i][j] += xv[i].x*wv[j].x + xv[i].y*wv[j].y + xv[i].z*wv[j].z + xv[i].w*wv[j].w;
    }
  }
  __syncthreads();
#pragma unroll
  for (int i = 0; i < 4; ++i)
#pragma unroll
    for (int j = 0; j < 4; ++j)
      xs[(tm*4+i)*64 + tn*4+j] = acc[i][j];   // reuse xs as z-tile [64 rows][64 r]
  __syncthreads();
  const int w = t >> 6, l = t & 63;
  for (int rr = 0; rr < 16; ++rr){
    int r = w * 16 + rr;
    float v = xs[r*64 + l];
    float az = fabsf(v);
    int cnt = 0;
    for (int s = 1; s < 64; ++s){
      float o = __shfl(az, (l + s) & 63, 64);
      cnt += (o > az) ? 1 : 0;
    }
    // keep iff fewer than 16 strictly-greater |z| => az >= 16th-largest (ties kept, matches ref)
    zb[(size_t)(row0 + r) * 64 + l] = (cnt < 16) ? f2bf(v * 2.0f) : (u16)0;
  }
}

// ---- main fused GEMM: out = x@W^T (3-pass split-bf16 MFMA) + b + z_s@B^T (1-pass) ----
__global__ __launch_bounds__(256, 2) void gemm_main(
    const u16* __restrict__ Xhi, const u16* __restrict__ Xlo,
    const u16* __restrict__ Whi, const u16* __restrict__ Wlo,
    const u16* __restrict__ zb,  const u16* __restrict__ Bb,
    const float* __restrict__ bias, float* __restrict__ out)
{
  // [128 rows][64 k] bf16 tiles; 16B-chunk XOR swizzle c' = c ^ (row&7)
  __shared__ u16 sXh[128*64];
  __shared__ u16 sXl[128*64];
  __shared__ u16 sWh[128*64];
  __shared__ u16 sWl[128*64];
  const int t = threadIdx.x;
  const int bid = blockIdx.x;
  const int bm = bid >> 4, bn = bid & 15;
  const size_t m0 = (size_t)bm * 128, n0 = (size_t)bn * 128;
  const int l = t & 63, w = t >> 6;
  const int wm = w & 1, wn = w >> 1;
  const int l15 = l & 15, l4 = l >> 4;
  f32x4 acc[4][4] = {};

  const u16* Xh_b = Xhi + m0 * DIN;
  const u16* Xl_b = Xlo + m0 * DIN;
  const u16* Wh_b = Whi + n0 * DIN;
  const u16* Wl_b = Wlo + n0 * DIN;

  for (int kc = 0; kc < 32; ++kc){
    const int k0 = kc * 64;
#pragma unroll
    for (int rep = 0; rep < 4; ++rep){
      const int idx = rep * 256 + t;
      const int r = idx >> 3, c = idx & 7;
      const int cp = c ^ (r & 7);                  // pre-swizzled global source (m173 pattern)
      const size_t goff = (size_t)r * DIN + k0 + cp * 8;
      const int ldsoff = (rep*256 + (t & ~63)) * 8; // wave-uniform base; HW scatters lane*16B
      gload16(Xh_b + goff, sXh + ldsoff);
      gload16(Xl_b + goff, sXl + ldsoff);
      gload16(Wh_b + goff, sWh + ldsoff);
      gload16(Wl_b + goff, sWl + ldsoff);
    }
    __syncthreads();
#pragma unroll
    for (int ks = 0; ks < 2; ++ks){
      short8 ah[4], al[4], bh[4], bl[4];
#pragma unroll
      for (int m = 0; m < 4; ++m){
        int r = wm*64 + m*16 + l15;
        int off = r*64 + (((ks*4 + l4) ^ (r & 7)) * 8);
        ah[m] = *(const short8*)(sXh + off);
        al[m] = *(const short8*)(sXl + off);
      }
#pragma unroll
      for (int n = 0; n < 4; ++n){
        int r = wn*64 + n*16 + l15;
        int off = r*64 + (((ks*4 + l4) ^ (r & 7)) * 8);
        bh[n] = *(const short8*)(sWh + off);
        bl[n] = *(const short8*)(sWl + off);
      }
#pragma unroll
      for (int m = 0; m < 4; ++m)
#pragma unroll
        for (int n = 0; n < 4; ++n){
          acc[m][n] = __builtin_amdgcn_mfma_f32_16x16x32_bf16(ah[m], bh[n], acc[m][n], 0, 0, 0);
          acc[m][n] = __builtin_amdgcn_mfma_f32_16x16x32_bf16(ah[m], bl[n], acc[m][n], 0, 0, 0);
          acc[m][n] = __builtin_amdgcn_mfma_f32_16x16x32_bf16(al[m], bh[n], acc[m][n], 0, 0, 0);
        }
    }
    __syncthreads();
  }

  // LoRA up-projection: one K=64 step, single-pass bf16 (z pre-scaled by 2.0)
  {
#pragma unroll
    for (int rep = 0; rep < 4; ++rep){
      const int idx = rep * 256 + t;
      const int r = idx >> 3, c = idx & 7;
      const int cp = c ^ (r & 7);
      const int ldsoff = (rep*256 + (t & ~63)) * 8;
      gload16(zb + (m0 + r) * 64 + cp * 8, sXh + ldsoff);
      gload16(Bb + (n0 + r) * 64 + cp * 8, sWh + ldsoff);
    }
    __syncthreads();
#pragma unroll
    for (int ks = 0; ks < 2; ++ks){
      short8 ah[4], bh[4];
#pragma unroll
      for (int m = 0; m < 4; ++m){
        int r = wm*64 + m*16 + l15;
        ah[m] = *(const short8*)(sXh + r*64 + (((ks*4 + l4) ^ (r & 7)) * 8));
      }
#pragma unroll
      for (int n = 0; n < 4; ++n){
        int r = wn*64 + n*16 + l15;
        bh[n] = *(const short8*)(sWh + r*64 + (((ks*4 + l4) ^ (r & 7)) * 8));
      }
#pragma unroll
      for (int m = 0; m < 4; ++m)
#pragma unroll
        for (int n = 0; n < 4; ++n)
          acc[m][n] = __builtin_amdgcn_mfma_f32_16x16x32_bf16(ah[m], bh[n], acc[m][n], 0, 0, 0);
    }
  }

  // epilogue: + bias, store. C/D layout: col=lane&15, row=(lane>>4)*4+reg  [m89]
  const int cb = (int)n0 + wn*64 + l15;
  float bbv[4];
#pragma unroll
  for (int n = 0; n < 4; ++n) bbv[n] = bias[cb + n*16];
#pragma unroll
  for (int m = 0; m < 4; ++m){
    size_t r0 = m0 + wm*64 + m*16 + l4*4;
#pragma unroll
    for (int e = 0; e < 4; ++e){
      float* orow = out + (r0 + e) * DOUT;
#pragma unroll
      for (int n = 0; n < 4; ++n)
        orow[cb + n*16] = acc[m][n][e] + bbv[n];
    }
  }
}

extern "C" void kernel_launch(void* const* d_in, const int* in_sizes, int n_in,
                              void* d_out, int out_size, void* d_ws, size_t ws_size,
                              hipStream_t stream) {
  const float* x    = (const float*)d_in[0];
  const float* A    = (const float*)d_in[1];
  const float* B    = (const float*)d_in[2];
  const float* W    = (const float*)d_in[3];
  const float* bias = (const float*)d_in[4];
  float* out = (float*)d_out;

  char* ws = (char*)d_ws;
  // layout (bytes): zb 2MB | Bb 256KB | Whi 8MB | Wlo 8MB | Xhi 64MB | Xlo 64MB  (~146.3 MiB)
  u16* zb  = (u16*)(ws);
  u16* Bb  = (u16*)(ws + 2097152);
  u16* Whi = (u16*)(ws + 2359296);
  u16* Wlo = (u16*)(ws + 10747904);
  u16* Xhi = (u16*)(ws + 19136512);
  u16* Xlo = (u16*)(ws + 86245376);

  conv_hilo<<<4096, 256, 0, stream>>>(W, Whi, Wlo);        // 2048*2048/1024
  conv_bf  <<<512, 256, 0, stream>>>(B, Bb);               // 2048*64/256
  zk       <<<256, 256, 0, stream>>>(x, A, Xhi, Xlo, zb);  // 64 rows/block
  gemm_main<<<2048, 256, 0, stream>>>(Xhi, Xlo, Whi, Wlo, zb, Bb, bias, out); // 128x16 tiles
}

// Round 6
// 694.224 us; speedup vs baseline: 1.1339x; 1.1339x over previous
//
#include <hip/hip_runtime.h>
#include <hip/hip_bf16.h>

#define M_TOT 16384
#define DIN 2048
#define DOUT 2048

typedef unsigned short u16;
typedef __attribute__((ext_vector_type(8))) short short8;
typedef __attribute__((ext_vector_type(4))) float f32x4;

__device__ __forceinline__ u16 f2bf(float f){
  union { __hip_bfloat16 h; u16 u; } c; c.h = __float2bfloat16(f); return c.u;
}
__device__ __forceinline__ float bf2f(u16 v){
  union { __hip_bfloat16 h; u16 u; } c; c.u = v; return __bfloat162float(c.h);
}

__device__ __forceinline__ void gload16(const void* g, void* lds){
  __builtin_amdgcn_global_load_lds((const __attribute__((address_space(1))) unsigned int*)g,
                                   (__attribute__((address_space(3))) unsigned int*)lds, 16, 0, 0);
}

// ---- W fp32 -> (hi,lo) bf16 split, 4 elems/thread ----
__global__ __launch_bounds__(256) void conv_hilo(const float* __restrict__ src,
                                                 u16* __restrict__ hi, u16* __restrict__ lo){
  size_t i = ((size_t)blockIdx.x * 256 + threadIdx.x) * 4;
  float4 v = *(const float4*)(src + i);
  float vv[4] = {v.x, v.y, v.z, v.w};
  u16 hh[4], ll[4];
#pragma unroll
  for (int e = 0; e < 4; ++e){
    u16 hb = f2bf(vv[e]); hh[e] = hb; ll[e] = f2bf(vv[e] - bf2f(hb));
  }
  *(ushort4*)(hi + i) = make_ushort4(hh[0],hh[1],hh[2],hh[3]);
  *(ushort4*)(lo + i) = make_ushort4(ll[0],ll[1],ll[2],ll[3]);
}

// ---- B fp32 -> bf16 ----
__global__ __launch_bounds__(256) void conv_bf(const float* __restrict__ src, u16* __restrict__ dst){
  int i = blockIdx.x * 256 + threadIdx.x;
  dst[i] = f2bf(src[i]);
}

// ---- zk3: fp32 z = x@A^T, BIT-IDENTICAL per-output sum order to the round-2
//      passing kernel (same fold expression, ascending k4, one thread/output).
//      32 rows/block -> 512 blocks = 2 blocks/CU. Micro-tile 2x4, register
//      prefetch (T14), swizzled fp32 LDS tiles (broadcast/2-way only).
//      Emits Xhi/Xlo split of x (x read exactly once). ----
__global__ __launch_bounds__(256, 2) void zk3(const float* __restrict__ x, const float* __restrict__ A,
                                              u16* __restrict__ Xhi, u16* __restrict__ Xlo,
                                              u16* __restrict__ zb){
  __shared__ float xs[32*64];   // x tile, float4-slot swizzle: slot' = sl ^ ((r>>1)&15)
  __shared__ float As[64*64];   // A tile, float4-slot swizzle: slot' = sl ^ (r>>2)
  __shared__ float zs[32*68];   // z tile (+4 pad)
  const int t = threadIdx.x;
  const int row0 = blockIdx.x * 32;
  const int tm = t >> 4, tn = t & 15;   // 16 row-groups x 16 col-groups; micro 2x4
  float acc[2][4] = {};

  float4 rx[2], ra[4];
  // prologue: load chunk 0
#pragma unroll
  for (int rep = 0; rep < 2; ++rep){
    int idx = rep*256 + t; int r = idx >> 4, sl = idx & 15;
    rx[rep] = *(const float4*)(x + (size_t)(row0 + r)*DIN + sl*4);
  }
#pragma unroll
  for (int rep = 0; rep < 4; ++rep){
    int idx = rep*256 + t; int r = idx >> 4, sl = idx & 15;
    ra[rep] = *(const float4*)(A + (size_t)r*DIN + sl*4);
  }

  for (int kc = 0; kc < 32; ++kc){
    const int k0 = kc * 64;
    // ---- stage x: hi/lo convert -> global Xhi/Xlo, fp32 -> LDS (swizzled) ----
#pragma unroll
    for (int rep = 0; rep < 2; ++rep){
      int idx = rep*256 + t; int r = idx >> 4, sl = idx & 15;
      float4 v = rx[rep];
      float vv[4] = {v.x, v.y, v.z, v.w};
      u16 hh[4], ll[4];
#pragma unroll
      for (int e = 0; e < 4; ++e){
        u16 hb = f2bf(vv[e]); hh[e] = hb; ll[e] = f2bf(vv[e] - bf2f(hb));
      }
      size_t go = (size_t)(row0 + r)*DIN + k0 + sl*4;
      *(ushort4*)(Xhi + go) = make_ushort4(hh[0],hh[1],hh[2],hh[3]);
      *(ushort4*)(Xlo + go) = make_ushort4(ll[0],ll[1],ll[2],ll[3]);
      int slX = sl ^ ((r >> 1) & 15);
      *(float4*)&xs[r*64 + slX*4] = v;
    }
    // ---- stage A (fp32, swizzled) ----
#pragma unroll
    for (int rep = 0; rep < 4; ++rep){
      int idx = rep*256 + t; int r = idx >> 4, sl = idx & 15;
      int slA = sl ^ (r >> 2);
      *(float4*)&As[r*64 + slA*4] = ra[rep];
    }
    // ---- T14: prefetch next chunk's globals (latency hides under FMA) ----
    if (kc != 31){
      const int k1 = k0 + 64;
#pragma unroll
      for (int rep = 0; rep < 2; ++rep){
        int idx = rep*256 + t; int r = idx >> 4, sl = idx & 15;
        rx[rep] = *(const float4*)(x + (size_t)(row0 + r)*DIN + k1 + sl*4);
      }
#pragma unroll
      for (int rep = 0; rep < 4; ++rep){
        int idx = rep*256 + t; int r = idx >> 4, sl = idx & 15;
        ra[rep] = *(const float4*)(A + (size_t)r*DIN + k1 + sl*4);
      }
    }
    __syncthreads();
    // ---- fp32 micro-GEMM: EXACT round-2 fold expression per output ----
#pragma unroll
    for (int k4 = 0; k4 < 16; ++k4){
      float4 xv[2], wv[4];
#pragma unroll
      for (int i = 0; i < 2; ++i)
        xv[i] = *(const float4*)&xs[(tm*2+i)*64 + ((k4 ^ tm) & 15)*4];
#pragma unroll
      for (int j = 0; j < 4; ++j)
        wv[j] = *(const float4*)&As[(tn*4+j)*64 + ((k4 ^ tn) & 15)*4];
#pragma unroll
      for (int i = 0; i < 2; ++i)
#pragma unroll
        for (int j = 0; j < 4; ++j)
          acc[i][j] += xv[i].x*wv[j].x + xv[i].y*wv[j].y + xv[i].z*wv[j].z + xv[i].w*wv[j].w;
    }
    __syncthreads();
  }

  // ---- z -> LDS ----
#pragma unroll
  for (int i = 0; i < 2; ++i)
#pragma unroll
    for (int j = 0; j < 4; ++j)
      zs[(tm*2+i)*68 + tn*4+j] = acc[i][j];
  __syncthreads();

  // ---- top-16 rank-select per row (count-strictly-greater < 16 keeps ties) ----
  const int w = t >> 6, l = t & 63;
  for (int rr = 0; rr < 8; ++rr){
    int r = w*8 + rr;
    float v = zs[r*68 + l];
    float az = fabsf(v);
    int cnt = 0;
    for (int s = 1; s < 64; ++s){
      float o = __shfl(az, (l + s) & 63, 64);
      cnt += (o > az) ? 1 : 0;
    }
    zb[(size_t)(row0 + r)*64 + l] = (cnt < 16) ? f2bf(v * 2.0f) : (u16)0;
  }
}

// ---- main fused GEMM: out = x@W^T (3-pass split-bf16 MFMA) + b + z_s@B^T (1-pass) ----
// BYTE-IDENTICAL to the round-2 passing version (362us, MfmaUtil 52%, 0 conflicts).
__global__ __launch_bounds__(256, 2) void gemm_main(
    const u16* __restrict__ Xhi, const u16* __restrict__ Xlo,
    const u16* __restrict__ Whi, const u16* __restrict__ Wlo,
    const u16* __restrict__ zb,  const u16* __restrict__ Bb,
    const float* __restrict__ bias, float* __restrict__ out)
{
  __shared__ u16 sXh[128*64];
  __shared__ u16 sXl[128*64];
  __shared__ u16 sWh[128*64];
  __shared__ u16 sWl[128*64];
  const int t = threadIdx.x;
  const int bid = blockIdx.x;
  const int bm = bid >> 4, bn = bid & 15;
  const size_t m0 = (size_t)bm * 128, n0 = (size_t)bn * 128;
  const int l = t & 63, w = t >> 6;
  const int wm = w & 1, wn = w >> 1;
  const int l15 = l & 15, l4 = l >> 4;
  f32x4 acc[4][4] = {};

  const u16* Xh_b = Xhi + m0 * DIN;
  const u16* Xl_b = Xlo + m0 * DIN;
  const u16* Wh_b = Whi + n0 * DIN;
  const u16* Wl_b = Wlo + n0 * DIN;

  for (int kc = 0; kc < 32; ++kc){
    const int k0 = kc * 64;
#pragma unroll
    for (int rep = 0; rep < 4; ++rep){
      const int idx = rep * 256 + t;
      const int r = idx >> 3, c = idx & 7;
      const int cp = c ^ (r & 7);
      const size_t goff = (size_t)r * DIN + k0 + cp * 8;
      const int ldsoff = (rep*256 + (t & ~63)) * 8;
      gload16(Xh_b + goff, sXh + ldsoff);
      gload16(Xl_b + goff, sXl + ldsoff);
      gload16(Wh_b + goff, sWh + ldsoff);
      gload16(Wl_b + goff, sWl + ldsoff);
    }
    __syncthreads();
#pragma unroll
    for (int ks = 0; ks < 2; ++ks){
      short8 ah[4], al[4], bh[4], bl[4];
#pragma unroll
      for (int m = 0; m < 4; ++m){
        int r = wm*64 + m*16 + l15;
        int off = r*64 + (((ks*4 + l4) ^ (r & 7)) * 8);
        ah[m] = *(const short8*)(sXh + off);
        al[m] = *(const short8*)(sXl + off);
      }
#pragma unroll
      for (int n = 0; n < 4; ++n){
        int r = wn*64 + n*16 + l15;
        int off = r*64 + (((ks*4 + l4) ^ (r & 7)) * 8);
        bh[n] = *(const short8*)(sWh + off);
        bl[n] = *(const short8*)(sWl + off);
      }
#pragma unroll
      for (int m = 0; m < 4; ++m)
#pragma unroll
        for (int n = 0; n < 4; ++n){
          acc[m][n] = __builtin_amdgcn_mfma_f32_16x16x32_bf16(ah[m], bh[n], acc[m][n], 0, 0, 0);
          acc[m][n] = __builtin_amdgcn_mfma_f32_16x16x32_bf16(ah[m], bl[n], acc[m][n], 0, 0, 0);
          acc[m][n] = __builtin_amdgcn_mfma_f32_16x16x32_bf16(al[m], bh[n], acc[m][n], 0, 0, 0);
        }
    }
    __syncthreads();
  }

  // LoRA up-projection: one K=64 step, single-pass bf16 (z pre-scaled by 2.0)
  {
#pragma unroll
    for (int rep = 0; rep < 4; ++rep){
      const int idx = rep * 256 + t;
      const int r = idx >> 3, c = idx & 7;
      const int cp = c ^ (r & 7);
      const int ldsoff = (rep*256 + (t & ~63)) * 8;
      gload16(zb + (m0 + r) * 64 + cp * 8, sXh + ldsoff);
      gload16(Bb + (n0 + r) * 64 + cp * 8, sWh + ldsoff);
    }
    __syncthreads();
#pragma unroll
    for (int ks = 0; ks < 2; ++ks){
      short8 ah[4], bh[4];
#pragma unroll
      for (int m = 0; m < 4; ++m){
        int r = wm*64 + m*16 + l15;
        ah[m] = *(const short8*)(sXh + r*64 + (((ks*4 + l4) ^ (r & 7)) * 8));
      }
#pragma unroll
      for (int n = 0; n < 4; ++n){
        int r = wn*64 + n*16 + l15;
        bh[n] = *(const short8*)(sWh + r*64 + (((ks*4 + l4) ^ (r & 7)) * 8));
      }
#pragma unroll
      for (int m = 0; m < 4; ++m)
#pragma unroll
        for (int n = 0; n < 4; ++n)
          acc[m][n] = __builtin_amdgcn_mfma_f32_16x16x32_bf16(ah[m], bh[n], acc[m][n], 0, 0, 0);
    }
  }

  // epilogue: + bias, store. C/D layout: col=lane&15, row=(lane>>4)*4+reg [m89]
  const int cb = (int)n0 + wn*64 + l15;
  float bbv[4];
#pragma unroll
  for (int n = 0; n < 4; ++n) bbv[n] = bias[cb + n*16];
#pragma unroll
  for (int m = 0; m < 4; ++m){
    size_t r0 = m0 + wm*64 + m*16 + l4*4;
#pragma unroll
    for (int e = 0; e < 4; ++e){
      float* orow = out + (r0 + e) * DOUT;
#pragma unroll
      for (int n = 0; n < 4; ++n)
        orow[cb + n*16] = acc[m][n][e] + bbv[n];
    }
  }
}

extern "C" void kernel_launch(void* const* d_in, const int* in_sizes, int n_in,
                              void* d_out, int out_size, void* d_ws, size_t ws_size,
                              hipStream_t stream) {
  const float* x    = (const float*)d_in[0];
  const float* A    = (const float*)d_in[1];
  const float* B    = (const float*)d_in[2];
  const float* W    = (const float*)d_in[3];
  const float* bias = (const float*)d_in[4];
  float* out = (float*)d_out;

  char* ws = (char*)d_ws;
  // layout (bytes): zb 2MB | Bb 256KB | Whi 8MB | Wlo 8MB | Xhi 64MB | Xlo 64MB  (~146.3 MiB)
  u16* zb  = (u16*)(ws);
  u16* Bb  = (u16*)(ws + 2097152);
  u16* Whi = (u16*)(ws + 2359296);
  u16* Wlo = (u16*)(ws + 10747904);
  u16* Xhi = (u16*)(ws + 19136512);
  u16* Xlo = (u16*)(ws + 86245376);

  conv_hilo<<<4096, 256, 0, stream>>>(W, Whi, Wlo);          // W: 2048*2048/1024
  conv_bf  <<<512, 256, 0, stream>>>(B, Bb);                 // B: 2048*64/256
  zk3      <<<512, 256, 0, stream>>>(x, A, Xhi, Xlo, zb);    // 32 rows/block, 2 blocks/CU
  gemm_main<<<2048, 256, 0, stream>>>(Xhi, Xlo, Whi, Wlo, zb, Bb, bias, out); // 128x16 tiles
}

// Round 9
// 499.623 us; speedup vs baseline: 1.5756x; 1.3895x over previous
//
#include <hip/hip_runtime.h>
#include <hip/hip_bf16.h>

#define M_TOT 16384
#define DIN 2048
#define DOUT 2048

typedef unsigned short u16;
typedef __attribute__((ext_vector_type(8))) short short8;
typedef __attribute__((ext_vector_type(4))) float f32x4;

__device__ __forceinline__ u16 f2bf(float f){
  union { __hip_bfloat16 h; u16 u; } c; c.h = __float2bfloat16(f); return c.u;
}
__device__ __forceinline__ float bf2f(u16 v){
  union { __hip_bfloat16 h; u16 u; } c; c.u = v; return __bfloat162float(c.h);
}

__device__ __forceinline__ void gload16(const void* g, void* lds){
  __builtin_amdgcn_global_load_lds((const __attribute__((address_space(1))) unsigned int*)g,
                                   (__attribute__((address_space(3))) unsigned int*)lds, 16, 0, 0);
}

// ---- W fp32 -> bf16, 4 elems/thread (1-pass main GEMM needs only hi) ----
__global__ __launch_bounds__(256) void conv_wb(const float* __restrict__ src, u16* __restrict__ dst){
  size_t i = ((size_t)blockIdx.x * 256 + threadIdx.x) * 4;
  float4 v = *(const float4*)(src + i);
  *(ushort4*)(dst + i) = make_ushort4(f2bf(v.x), f2bf(v.y), f2bf(v.z), f2bf(v.w));
}

// ---- B fp32 -> bf16 ----
__global__ __launch_bounds__(256) void conv_bf(const float* __restrict__ src, u16* __restrict__ dst){
  int i = blockIdx.x * 256 + threadIdx.x;
  dst[i] = f2bf(src[i]);
}

// ---- zk4: fp32 z = x@A^T, BIT-IDENTICAL per-output fold to the round-2/6
//      passing kernels (same expression text, ascending kc/k4, one thread per
//      output). 512 threads, 32 rows/block, 512 blocks -> 16 waves/CU
//      (4/SIMD, vs zk3's 2/SIMD — the measured ~320us was issue/LDS-stall
//      bound at low occupancy). Micro 2x2 (4 outputs/thread). Thread map
//      tm=t&15 (row-pair), tn=t>>4 (col-pair): xv reads 2-way, wv broadcast.
//      Emits Xb bf16 (x read exactly once); no Xlo anymore. ----
__global__ __launch_bounds__(512, 4) void zk4(const float* __restrict__ x, const float* __restrict__ A,
                                              u16* __restrict__ Xb, u16* __restrict__ zb){
  __shared__ float xs[32*64];   // x tile, float4-slot swizzle: slot' = sl ^ ((r>>1)&15)
  __shared__ float As[64*64];   // A tile, float4-slot swizzle: slot' = sl ^ ((r>>2)&15)
  __shared__ float zs[32*68];   // z tile (+4 pad)
  const int t = threadIdx.x;
  const int row0 = blockIdx.x * 32;
  const int tm = t & 15;        // row-pair index: rows tm*2, tm*2+1
  const int tn = t >> 4;        // col-pair index: cols tn*2, tn*2+1
  float acc[2][2] = {};

  const int sr = t >> 4;        // x-stage row 0..31
  const int ss = t & 15;        // x-stage slot 0..15
  float4 rx;
  float4 ra[2];
  // prologue: load chunk 0
  rx = *(const float4*)(x + (size_t)(row0 + sr)*DIN + ss*4);
#pragma unroll
  for (int rep = 0; rep < 2; ++rep){
    int idx = rep*512 + t; int r = idx >> 4, sl = idx & 15;
    ra[rep] = *(const float4*)(A + (size_t)r*DIN + sl*4);
  }

  for (int kc = 0; kc < 32; ++kc){
    const int k0 = kc * 64;
    // ---- stage x: bf16 convert -> global Xb, fp32 -> LDS (swizzled) ----
    {
      float4 v = rx;
      size_t go = (size_t)(row0 + sr)*DIN + k0 + ss*4;
      *(ushort4*)(Xb + go) = make_ushort4(f2bf(v.x), f2bf(v.y), f2bf(v.z), f2bf(v.w));
      int slX = ss ^ ((sr >> 1) & 15);
      *(float4*)&xs[sr*64 + slX*4] = v;
    }
    // ---- stage A (fp32, swizzled) ----
#pragma unroll
    for (int rep = 0; rep < 2; ++rep){
      int idx = rep*512 + t; int r = idx >> 4, sl = idx & 15;
      int slA = sl ^ ((r >> 2) & 15);
      *(float4*)&As[r*64 + slA*4] = ra[rep];
    }
    // ---- T14: prefetch next chunk's globals (latency hides under FMA) ----
    if (kc != 31){
      const int k1 = k0 + 64;
      rx = *(const float4*)(x + (size_t)(row0 + sr)*DIN + k1 + ss*4);
#pragma unroll
      for (int rep = 0; rep < 2; ++rep){
        int idx = rep*512 + t; int r = idx >> 4, sl = idx & 15;
        ra[rep] = *(const float4*)(A + (size_t)r*DIN + k1 + sl*4);
      }
    }
    __syncthreads();
    // ---- fp32 micro-GEMM: EXACT same fold expression per output as rounds 2/6 ----
#pragma unroll
    for (int k4 = 0; k4 < 16; ++k4){
      float4 xv[2], wv[2];
#pragma unroll
      for (int i = 0; i < 2; ++i)
        xv[i] = *(const float4*)&xs[(tm*2+i)*64 + ((k4 ^ tm) & 15)*4];
#pragma unroll
      for (int j = 0; j < 2; ++j)
        wv[j] = *(const float4*)&As[(tn*2+j)*64 + ((k4 ^ (tn >> 1)) & 15)*4];
#pragma unroll
      for (int i = 0; i < 2; ++i)
#pragma unroll
        for (int j = 0; j < 2; ++j)
          acc[i][j] += xv[i].x*wv[j].x + xv[i].y*wv[j].y + xv[i].z*wv[j].z + xv[i].w*wv[j].w;
    }
    __syncthreads();
  }

  // ---- z -> LDS ----
#pragma unroll
  for (int i = 0; i < 2; ++i)
#pragma unroll
    for (int j = 0; j < 2; ++j)
      zs[(tm*2+i)*68 + tn*2+j] = acc[i][j];
  __syncthreads();

  // ---- top-16 rank-select per row (count-strictly-greater < 16 keeps ties) ----
  const int w = t >> 6, l = t & 63;
  for (int rr = 0; rr < 4; ++rr){
    int r = w*4 + rr;
    float v = zs[r*68 + l];
    float az = fabsf(v);
    int cnt = 0;
    for (int s = 1; s < 64; ++s){
      float o = __shfl(az, (l + s) & 63, 64);
      cnt += (o > az) ? 1 : 0;
    }
    zb[(size_t)(row0 + r)*64 + l] = (cnt < 16) ? f2bf(v * 2.0f) : (u16)0;
  }
}

// ---- main fused GEMM, 1-pass bf16: out = bf16(x)@bf16(W)^T + b + z_s@B^T.
//      Dropped-term error (xl*w + xh*wl) ~1.6e-3 RMS, ~9e-3 absmax over 33.5M
//      outputs — linear path, no selection amplification; threshold 0.122.
//      2 staged tiles -> LDS 32KB -> 4 blocks/CU (16 waves/CU). ----
__global__ __launch_bounds__(256, 4) void gemm1p(
    const u16* __restrict__ Xb, const u16* __restrict__ Wb,
    const u16* __restrict__ zb, const u16* __restrict__ Bb,
    const float* __restrict__ bias, float* __restrict__ out)
{
  __shared__ u16 sX[128*64];
  __shared__ u16 sW[128*64];
  const int t = threadIdx.x;
  const int bid = blockIdx.x;
  const int bm = bid >> 4, bn = bid & 15;
  const size_t m0 = (size_t)bm * 128, n0 = (size_t)bn * 128;
  const int l = t & 63, w = t >> 6;
  const int wm = w & 1, wn = w >> 1;
  const int l15 = l & 15, l4 = l >> 4;
  f32x4 acc[4][4] = {};

  const u16* X_b = Xb + m0 * DIN;
  const u16* W_b = Wb + n0 * DIN;

  for (int kc = 0; kc < 32; ++kc){
    const int k0 = kc * 64;
#pragma unroll
    for (int rep = 0; rep < 4; ++rep){
      const int idx = rep * 256 + t;
      const int r = idx >> 3, c = idx & 7;
      const int cp = c ^ (r & 7);                  // pre-swizzled global source
      const size_t goff = (size_t)r * DIN + k0 + cp * 8;
      const int ldsoff = (rep*256 + (t & ~63)) * 8; // wave-uniform base
      gload16(X_b + goff, sX + ldsoff);
      gload16(W_b + goff, sW + ldsoff);
    }
    __syncthreads();
#pragma unroll
    for (int ks = 0; ks < 2; ++ks){
      short8 av[4], bv[4];
#pragma unroll
      for (int m = 0; m < 4; ++m){
        int r = wm*64 + m*16 + l15;
        av[m] = *(const short8*)(sX + r*64 + (((ks*4 + l4) ^ (r & 7)) * 8));
      }
#pragma unroll
      for (int n = 0; n < 4; ++n){
        int r = wn*64 + n*16 + l15;
        bv[n] = *(const short8*)(sW + r*64 + (((ks*4 + l4) ^ (r & 7)) * 8));
      }
#pragma unroll
      for (int m = 0; m < 4; ++m)
#pragma unroll
        for (int n = 0; n < 4; ++n)
          acc[m][n] = __builtin_amdgcn_mfma_f32_16x16x32_bf16(av[m], bv[n], acc[m][n], 0, 0, 0);
    }
    __syncthreads();
  }

  // LoRA up-projection: one K=64 step, single-pass bf16 (z pre-scaled by 2.0)
  {
#pragma unroll
    for (int rep = 0; rep < 4; ++rep){
      const int idx = rep * 256 + t;
      const int r = idx >> 3, c = idx & 7;
      const int cp = c ^ (r & 7);
      const int ldsoff = (rep*256 + (t & ~63)) * 8;
      gload16(zb + (m0 + r) * 64 + cp * 8, sX + ldsoff);
      gload16(Bb + (n0 + r) * 64 + cp * 8, sW + ldsoff);
    }
    __syncthreads();
#pragma unroll
    for (int ks = 0; ks < 2; ++ks){
      short8 av[4], bv[4];
#pragma unroll
      for (int m = 0; m < 4; ++m){
        int r = wm*64 + m*16 + l15;
        av[m] = *(const short8*)(sX + r*64 + (((ks*4 + l4) ^ (r & 7)) * 8));
      }
#pragma unroll
      for (int n = 0; n < 4; ++n){
        int r = wn*64 + n*16 + l15;
        bv[n] = *(const short8*)(sW + r*64 + (((ks*4 + l4) ^ (r & 7)) * 8));
      }
#pragma unroll
      for (int m = 0; m < 4; ++m)
#pragma unroll
        for (int n = 0; n < 4; ++n)
          acc[m][n] = __builtin_amdgcn_mfma_f32_16x16x32_bf16(av[m], bv[n], acc[m][n], 0, 0, 0);
    }
  }

  // epilogue: + bias, store. C/D layout: col=lane&15, row=(lane>>4)*4+reg [m89]
  const int cb = (int)n0 + wn*64 + l15;
  float bbv[4];
#pragma unroll
  for (int n = 0; n < 4; ++n) bbv[n] = bias[cb + n*16];
#pragma unroll
  for (int m = 0; m < 4; ++m){
    size_t r0 = m0 + wm*64 + m*16 + l4*4;
#pragma unroll
    for (int e = 0; e < 4; ++e){
      float* orow = out + (r0 + e) * DOUT;
#pragma unroll
      for (int n = 0; n < 4; ++n)
        orow[cb + n*16] = acc[m][n][e] + bbv[n];
    }
  }
}

extern "C" void kernel_launch(void* const* d_in, const int* in_sizes, int n_in,
                              void* d_out, int out_size, void* d_ws, size_t ws_size,
                              hipStream_t stream) {
  const float* x    = (const float*)d_in[0];
  const float* A    = (const float*)d_in[1];
  const float* B    = (const float*)d_in[2];
  const float* W    = (const float*)d_in[3];
  const float* bias = (const float*)d_in[4];
  float* out = (float*)d_out;

  char* ws = (char*)d_ws;
  // layout (bytes): zb 2MB | Bb 256KB | Wb 8MB | (gap) | Xb 64MB
  u16* zb = (u16*)(ws);
  u16* Bb = (u16*)(ws + 2097152);
  u16* Wb = (u16*)(ws + 2359296);
  u16* Xb = (u16*)(ws + 19136512);

  conv_wb <<<4096, 256, 0, stream>>>(W, Wb);                 // W: 2048*2048/1024
  conv_bf <<<512, 256, 0, stream>>>(B, Bb);                  // B: 2048*64/256
  zk4     <<<512, 512, 0, stream>>>(x, A, Xb, zb);           // 32 rows/block, 16 waves/CU
  gemm1p  <<<2048, 256, 0, stream>>>(Xb, Wb, zb, Bb, bias, out); // 128x16 tiles
}